// Round 1
// baseline (75.703 us; speedup 1.0000x reference)
//
#include <hip/hip_runtime.h>
#include <math.h>

// YOLO detection-layer loss, exploiting sparsity: only the <=320 GT-marked
// cells contribute non-constant terms; the 277k unmarked cells contribute
// exactly (CELLS - n_marked) * ln(80) to loss_cls and nothing else.

namespace {
constexpr int BS    = 16;
constexpr int NGT   = 20;
constexpr int NBOX  = BS * NGT;          // 320
constexpr int NA    = 3;
constexpr int GS    = 76;
constexpr int PLANE = GS * GS;           // 5776
constexpr int NCLS  = 80;
constexpr int NATTR = 5 + NCLS;          // 85
constexpr int CELLS = BS * NA * PLANE;   // 277248
constexpr int BLK   = 512;
}

__device__ __forceinline__ float sigm(float v) { return 1.0f / (1.0f + expf(-v)); }

__global__ __launch_bounds__(BLK)
void yolo_loss_kernel(const float* __restrict__ x,
                      const float* __restrict__ y,
                      float* __restrict__ out)
{
    __shared__ int   s_lin[NBOX];
    __shared__ float s_txt[NBOX], s_tyt[NBOX], s_twt[NBOX], s_tht[NBOX], s_iou[NBOX];
    __shared__ int   s_cls[NBOX];
    __shared__ float red[7][BLK];

    // anchors / stride(=8): all exact in binary fp32
    const float aw[NA] = {1.25f, 2.0f, 4.125f};
    const float ah[NA] = {1.625f, 3.75f, 2.875f};

    const int tid = threadIdx.x;
    const int b  = tid / NGT;   // batch index (valid only for tid < NBOX)
    int best_a = 0, gi = 0, gj = 0;

    // -------- Phase 1: per-GT-box anchor assignment --------
    if (tid < NBOX) {
        const float* yt = y + (size_t)tid * 5;
        float gx = yt[0] * (float)GS;
        float gy = yt[1] * (float)GS;
        float gw = yt[2] * (float)GS;
        float gh = yt[3] * (float)GS;
        int   cl = (int)yt[4];
        gi = min(max((int)gx, 0), GS - 1);
        gj = min(max((int)gy, 0), GS - 1);

        // gt box in xyxy, area computed from xyxy exactly like the reference
        float gx1 = gx - gw * 0.5f, gy1 = gy - gh * 0.5f;
        float gx2 = gx + gw * 0.5f, gy2 = gy + gh * 0.5f;
        float garea = (gx2 - gx1) * (gy2 - gy1);

        const float* cell = x + (size_t)b * (NA * NATTR * PLANE) + (size_t)(gj * GS + gi);
        float best = -1.0f;
        for (int a = 0; a < NA; ++a) {
            const float* p = cell + (size_t)a * NATTR * PLANE;
            float bx = sigm(p[0])         + (float)gi;
            float by = sigm(p[PLANE])     + (float)gj;
            float bw = expf(p[2 * PLANE]) * aw[a];
            float bh = expf(p[3 * PLANE]) * ah[a];
            float px1 = bx - bw * 0.5f, py1 = by - bh * 0.5f;
            float px2 = bx + bw * 0.5f, py2 = by + bh * 0.5f;
            float ix1 = fmaxf(px1, gx1), iy1 = fmaxf(py1, gy1);
            float ix2 = fminf(px2, gx2), iy2 = fminf(py2, gy2);
            float inter = fmaxf(ix2 - ix1, 0.0f) * fmaxf(iy2 - iy1, 0.0f);
            float parea = (px2 - px1) * (py2 - py1);
            float iou = inter / (parea + garea - inter + 1e-16f);
            if (iou > best) { best = iou; best_a = a; }   // strict > == argmax-first tiebreak
        }
        s_lin[tid] = ((b * NA + best_a) * GS + gj) * GS + gi;
        s_txt[tid] = gx - (float)gi;
        s_tyt[tid] = gy - (float)gj;
        s_twt[tid] = logf(gw / aw[best_a]);
        s_tht[tid] = logf(gh / ah[best_a]);
        s_iou[tid] = best;
        s_cls[tid] = cl;
    }
    __syncthreads();

    // -------- Phase 2+3: dedup (scatter .set => LAST index wins) + losses --------
    float lx = 0.f, ly = 0.f, lw = 0.f, lh = 0.f, lcls = 0.f, lconf = 0.f, nwin = 0.f;
    if (tid < NBOX) {
        const int mylin = s_lin[tid];
        bool winner = true;
        for (int u = tid + 1; u < NBOX; ++u)
            if (s_lin[u] == mylin) { winner = false; break; }

        if (winner) {
            nwin = 1.0f;
            const float* p = x + (size_t)(b * NA * NATTR + best_a * NATTR) * PLANE
                               + (size_t)(gj * GS + gi);
            float ptx = sigm(p[0]);
            float pty = sigm(p[PLANE]);
            float ptw = p[2 * PLANE];
            float pth = p[3 * PLANE];
            float pcf = sigm(p[4 * PLANE]);

            float dx = ptx - s_txt[tid]; lx = dx * dx;
            float dy = pty - s_tyt[tid]; ly = dy * dy;
            float dw = ptw - s_twt[tid]; lw = dw * dw;
            float dh = pth - s_tht[tid]; lh = dh * dh;
            float dc = 5.0f * (pcf - s_iou[tid]); lconf = dc * dc;

            // cross-entropy: logsumexp over 80 classes minus picked logit
            const float* pc = p + (size_t)5 * PLANE;
            float m = -INFINITY;
            for (int c = 0; c < NCLS; ++c) m = fmaxf(m, pc[(size_t)c * PLANE]);
            float se = 0.0f;
            for (int c = 0; c < NCLS; ++c) se += expf(pc[(size_t)c * PLANE] - m);
            float lse = m + logf(se);
            lcls = lse - pc[(size_t)s_cls[tid] * PLANE];
        }
    }

    // -------- Reduction (BLK = 512, power of two) --------
    red[0][tid] = lx;   red[1][tid] = ly;   red[2][tid] = lw;  red[3][tid] = lh;
    red[4][tid] = lcls; red[5][tid] = lconf; red[6][tid] = nwin;
    __syncthreads();
    for (int s = BLK / 2; s > 0; s >>= 1) {
        if (tid < s) {
            #pragma unroll
            for (int k = 0; k < 7; ++k) red[k][tid] += red[k][tid + s];
        }
        __syncthreads();
    }

    if (tid == 0) {
        out[0] = red[0][0];
        out[1] = red[1][0];
        out[2] = red[2][0];
        out[3] = red[3][0];
        // unmarked cells: ml == 0 vector -> lse = ln(80), picked = 0
        double cls_const = (double)(CELLS - (int)(red[6][0] + 0.5f)) * log(80.0);
        out[4] = (float)((double)red[4][0] + cls_const);
        out[5] = red[5][0];
    }
}

extern "C" void kernel_launch(void* const* d_in, const int* in_sizes, int n_in,
                              void* d_out, int out_size, void* d_ws, size_t ws_size,
                              hipStream_t stream) {
    const float* x  = (const float*)d_in[0];   // (16, 255, 76, 76) fp32
    const float* y  = (const float*)d_in[1];   // (16, 20, 5) fp32
    float* out = (float*)d_out;                // 6 losses
    yolo_loss_kernel<<<1, BLK, 0, stream>>>(x, y, out);
}

// Round 2
// 37.053 us; speedup vs baseline: 2.0431x; 2.0431x over previous
//
#include <hip/hip_runtime.h>
#include <math.h>

// YOLO detection-layer loss — sparse formulation, latency spread across CUs.
// K1: one block per GT box (320 blocks) computes anchor assignment + all loss
//     partials speculatively (winner mask applied later). One parallel load
//     round for all 3 anchors x 85 attrs.
// K2: one block dedups lin indices (scatter .set => LAST box wins), masks,
//     reduces, adds the closed-form (CELLS - n_win)*ln(80) class constant.

namespace {
constexpr int BS    = 16;
constexpr int NGT   = 20;
constexpr int NBOX  = BS * NGT;          // 320
constexpr int NA    = 3;
constexpr int GS    = 76;
constexpr int PLANE = GS * GS;           // 5776
constexpr int NCLS  = 80;
constexpr int NATTR = 5 + NCLS;          // 85
constexpr int CELLS = BS * NA * PLANE;   // 277248
}

__device__ __forceinline__ float sigm(float v) { return 1.0f / (1.0f + expf(-v)); }

// ws layout: int lin[NBOX]; float L[NBOX][6]  (x,y,w,h,cls,conf)
__global__ __launch_bounds__(256)
void yolo_k1(const float* __restrict__ x, const float* __restrict__ y,
             int* __restrict__ lin_ws, float* __restrict__ loss_ws)
{
    const float aw[NA] = {1.25f, 2.0f, 4.125f};   // anchors / stride(=8), exact fp32
    const float ah[NA] = {1.625f, 3.75f, 2.875f};

    __shared__ float s_y[5];
    __shared__ float s_val[NA][NATTR];
    __shared__ int   s_best;

    const int box = blockIdx.x;        // 0..319
    const int b   = box / NGT;
    const int tid = threadIdx.x;

    // round 1: ground-truth row
    if (tid < 5) s_y[tid] = y[box * 5 + tid];
    __syncthreads();

    const float gx = s_y[0] * (float)GS, gy = s_y[1] * (float)GS;
    const float gw = s_y[2] * (float)GS, gh = s_y[3] * (float)GS;
    const int gi = min(max((int)gx, 0), GS - 1);
    const int gj = min(max((int)gy, 0), GS - 1);
    const int cell = gj * GS + gi;

    // round 2: all 3 anchors x 85 attrs of this cell, one load per thread
    if (tid < NA * NATTR) {
        const int a = tid / NATTR, k = tid % NATTR;
        s_val[a][k] = x[(size_t)((b * NA + a) * NATTR + k) * PLANE + cell];
    }
    __syncthreads();

    if (tid == 0) {
        const float gx1 = gx - gw * 0.5f, gy1 = gy - gh * 0.5f;
        const float gx2 = gx + gw * 0.5f, gy2 = gy + gh * 0.5f;
        const float garea = (gx2 - gx1) * (gy2 - gy1);
        float best = -1.0f; int ba = 0;
        for (int a = 0; a < NA; ++a) {
            float bx = sigm(s_val[a][0]) + (float)gi;
            float by = sigm(s_val[a][1]) + (float)gj;
            float bw = expf(s_val[a][2]) * aw[a];
            float bh = expf(s_val[a][3]) * ah[a];
            float px1 = bx - bw * 0.5f, py1 = by - bh * 0.5f;
            float px2 = bx + bw * 0.5f, py2 = by + bh * 0.5f;
            float ix1 = fmaxf(px1, gx1), iy1 = fmaxf(py1, gy1);
            float ix2 = fminf(px2, gx2), iy2 = fminf(py2, gy2);
            float inter = fmaxf(ix2 - ix1, 0.0f) * fmaxf(iy2 - iy1, 0.0f);
            float parea = (px2 - px1) * (py2 - py1);
            float iou = inter / (parea + garea - inter + 1e-16f);
            if (iou > best) { best = iou; ba = a; }   // strict > == first-max tiebreak
        }
        s_best = ba;
        lin_ws[box] = ((b * NA + ba) * GS + gj) * GS + gi;
        float dx = sigm(s_val[ba][0]) - (gx - (float)gi);
        float dy = sigm(s_val[ba][1]) - (gy - (float)gj);
        float dw = s_val[ba][2] - logf(gw / aw[ba]);
        float dh = s_val[ba][3] - logf(gh / ah[ba]);
        float dc = 5.0f * (sigm(s_val[ba][4]) - best);
        float* L = loss_ws + box * 6;
        L[0] = dx * dx; L[1] = dy * dy; L[2] = dw * dw; L[3] = dh * dh; L[5] = dc * dc;
    }
    __syncthreads();

    // wave 0: logsumexp over the best anchor's 80 class logits
    if (tid < 64) {
        const int ba = s_best;
        float v1 = s_val[ba][5 + tid];
        float v2 = (tid < NCLS - 64) ? s_val[ba][5 + 64 + tid] : -INFINITY;
        float m = fmaxf(v1, v2);
        #pragma unroll
        for (int off = 32; off; off >>= 1) m = fmaxf(m, __shfl_xor(m, off, 64));
        float s = expf(v1 - m) + ((tid < NCLS - 64) ? expf(v2 - m) : 0.0f);
        #pragma unroll
        for (int off = 32; off; off >>= 1) s += __shfl_xor(s, off, 64);
        if (tid == 0) {
            const int cl = (int)s_y[4];
            loss_ws[box * 6 + 4] = m + logf(s) - s_val[ba][5 + cl];
        }
    }
}

__global__ __launch_bounds__(512)
void yolo_k2(const int* __restrict__ lin_ws, const float* __restrict__ loss_ws,
             float* __restrict__ out)
{
    __shared__ int   s_lin[NBOX];
    __shared__ float red[7][512];
    const int tid = threadIdx.x;

    if (tid < NBOX) s_lin[tid] = lin_ws[tid];
    __syncthreads();

    float v[7] = {0.f, 0.f, 0.f, 0.f, 0.f, 0.f, 0.f};
    if (tid < NBOX) {
        const int my = s_lin[tid];
        bool win = true;
        for (int u = tid + 1; u < NBOX; ++u)
            if (s_lin[u] == my) { win = false; break; }   // last duplicate wins
        if (win) {
            const float* L = loss_ws + tid * 6;
            v[0] = L[0]; v[1] = L[1]; v[2] = L[2];
            v[3] = L[3]; v[4] = L[4]; v[5] = L[5];
            v[6] = 1.0f;
        }
    }
    #pragma unroll
    for (int k = 0; k < 7; ++k) red[k][tid] = v[k];
    __syncthreads();
    for (int s = 256; s > 0; s >>= 1) {
        if (tid < s) {
            #pragma unroll
            for (int k = 0; k < 7; ++k) red[k][tid] += red[k][tid + s];
        }
        __syncthreads();
    }

    if (tid == 0) {
        out[0] = red[0][0];
        out[1] = red[1][0];
        out[2] = red[2][0];
        out[3] = red[3][0];
        // unmarked cells: ml == 0 vector -> lse = ln(80), picked = 0
        double cls_const = (double)(CELLS - (int)(red[6][0] + 0.5f)) * log(80.0);
        out[4] = (float)((double)red[4][0] + cls_const);
        out[5] = red[5][0];
    }
}

extern "C" void kernel_launch(void* const* d_in, const int* in_sizes, int n_in,
                              void* d_out, int out_size, void* d_ws, size_t ws_size,
                              hipStream_t stream) {
    const float* x = (const float*)d_in[0];   // (16, 255, 76, 76) fp32
    const float* y = (const float*)d_in[1];   // (16, 20, 5) fp32
    float* out = (float*)d_out;               // 6 losses

    int*   lin_ws  = (int*)d_ws;                          // NBOX ints
    float* loss_ws = (float*)((char*)d_ws + NBOX * 4);    // NBOX*6 floats

    yolo_k1<<<NBOX, 256, 0, stream>>>(x, y, lin_ws, loss_ws);
    yolo_k2<<<1, 512, 0, stream>>>(lin_ws, loss_ws, out);
}